// Round 7
// baseline (314.865 us; speedup 1.0000x reference)
//
#include <hip/hip_runtime.h>
#include <hip/hip_bf16.h>

typedef unsigned short u16;
typedef unsigned int u32;
typedef __attribute__((ext_vector_type(8))) short bf16x8;
typedef __attribute__((ext_vector_type(4))) float f32x4;

#define AS1 __attribute__((address_space(1)))
#define AS3 __attribute__((address_space(3)))

#define M_DIM 8192
#define N_DIM 4096
#define K_DIM 4096
#define BM 128
#define BN 256
#define BK 32
#define NKT (K_DIM / BK)   // 128 K-tiles

static __device__ __forceinline__ void gload16(const u16* g, u16* l) {
    __builtin_amdgcn_global_load_lds((const AS1 void*)g, (AS3 void*)l, 16, 0, 0);
}

static __device__ __forceinline__ u16 f2bf_rne(float f) {
    u32 u = __float_as_uint(f);
    u32 r = (u + 0x7fffu + ((u >> 16) & 1u)) >> 16;
    return (u16)r;
}

// ---------------- Kernel 1: convert input fp32 -> bf16 ----------------
__global__ void cvt_a_kernel(const float* __restrict__ In, u16* __restrict__ Ab) {
    size_t i = ((size_t)blockIdx.x * 256 + threadIdx.x) * 8;
    float4 x0 = *(const float4*)(In + i);
    float4 x1 = *(const float4*)(In + i + 4);
    u16 o[8];
    o[0] = f2bf_rne(x0.x); o[1] = f2bf_rne(x0.y); o[2] = f2bf_rne(x0.z); o[3] = f2bf_rne(x0.w);
    o[4] = f2bf_rne(x1.x); o[5] = f2bf_rne(x1.y); o[6] = f2bf_rne(x1.z); o[7] = f2bf_rne(x1.w);
    *(ulong2*)(Ab + i) = *(const ulong2*)o;
}

// ---------------- Kernel 2: dequantize W -> bf16 ----------------
__global__ void dequant_w_kernel(const int* __restrict__ codes,
                                 const float* __restrict__ cbs,
                                 const float* __restrict__ scales,
                                 u16* __restrict__ Wb) {
    int g = blockIdx.x * 256 + threadIdx.x;
    int o = g >> 9;
    int c0 = codes[(size_t)g * 2 + 0];
    int c1 = codes[(size_t)g * 2 + 1];
    float s = scales[o];
    const float4* e0 = (const float4*)(cbs + (size_t)c0 * 8);
    const float4* e1 = (const float4*)(cbs + 2048 + (size_t)c1 * 8);
    float4 a0 = e0[0], a1 = e0[1];
    float4 b0 = e1[0], b1 = e1[1];
    u16 o8[8];
    o8[0] = f2bf_rne(s * (a0.x + b0.x));
    o8[1] = f2bf_rne(s * (a0.y + b0.y));
    o8[2] = f2bf_rne(s * (a0.z + b0.z));
    o8[3] = f2bf_rne(s * (a0.w + b0.w));
    o8[4] = f2bf_rne(s * (a1.x + b1.x));
    o8[5] = f2bf_rne(s * (a1.y + b1.y));
    o8[6] = f2bf_rne(s * (a1.z + b1.z));
    o8[7] = f2bf_rne(s * (a1.w + b1.w));
    *(ulong2*)(Wb + (size_t)g * 8) = *(const ulong2*)o8;
}

// ---------------- Kernel 3: 128x256 tile, BK=32, triple-buffer, 2 blocks/CU ----
// 256 thr = 4 waves (1M x 4N), per-wave 128x64 output = acc[8][4] 16x16x32 frags.
// LDS buf: A[128][32] (8KB, elems 0..4095) + B[256][32] (16KB, elems 4096..12287);
// 3 bufs = 72KB -> two blocks co-resident per CU in DIFFERENT barrier domains:
// their phase drift overlaps one block's MFMA with the other's ds_reads (m114).
// Swizzle: 16B col-block physically at (lq ^ ((row>>1)&3)) [round-5-verified 0-conflict],
// same XOR pre-applied to the GLOBAL source column for linear gload_lds (rule 21).

#define FENCE() asm volatile("" ::: "memory")
#define BAR()   __builtin_amdgcn_s_barrier()
#define WAIT_LGKM0() asm volatile("s_waitcnt lgkmcnt(0)" ::: "memory")
#define WAIT_VM12()  asm volatile("s_waitcnt vmcnt(12)" ::: "memory")
#define WAIT_VM6()   asm volatile("s_waitcnt vmcnt(6)" ::: "memory")
#define WAIT_VM0()   asm volatile("s_waitcnt vmcnt(0)" ::: "memory")
#define SCHEDB() __builtin_amdgcn_sched_barrier(0)

#define MFMA1(mf, nf) acc[mf][nf] = __builtin_amdgcn_mfma_f32_16x16x32_bf16(a[mf], b[nf], acc[mf][nf], 0, 0, 0)
#define MFMA32() do { \
    MFMA1(0, 0); MFMA1(0, 1); MFMA1(0, 2); MFMA1(0, 3); \
    MFMA1(1, 0); MFMA1(1, 1); MFMA1(1, 2); MFMA1(1, 3); \
    MFMA1(2, 0); MFMA1(2, 1); MFMA1(2, 2); MFMA1(2, 3); \
    MFMA1(3, 0); MFMA1(3, 1); MFMA1(3, 2); MFMA1(3, 3); \
    MFMA1(4, 0); MFMA1(4, 1); MFMA1(4, 2); MFMA1(4, 3); \
    MFMA1(5, 0); MFMA1(5, 1); MFMA1(5, 2); MFMA1(5, 3); \
    MFMA1(6, 0); MFMA1(6, 1); MFMA1(6, 2); MFMA1(6, 3); \
    MFMA1(7, 0); MFMA1(7, 1); MFMA1(7, 2); MFMA1(7, 3); \
} while (0)

// stage one K-tile (A 2 issues + B 4 issues, 16B/lane each) into buf P
#define STG6(P, koff) do { \
    gload16(pA0 + (koff), &ls[(P)*12288 + 0     + wOff]); \
    gload16(pA1 + (koff), &ls[(P)*12288 + 2048  + wOff]); \
    gload16(pB0 + (koff), &ls[(P)*12288 + 4096  + wOff]); \
    gload16(pB1 + (koff), &ls[(P)*12288 + 6144  + wOff]); \
    gload16(pB2 + (koff), &ls[(P)*12288 + 8192  + wOff]); \
    gload16(pB3 + (koff), &ls[(P)*12288 + 10240 + wOff]); \
} while (0)

#define STG_NONE() do { } while (0)

#define PHASE(P, STG_EXPR, VMW) do { \
    STG_EXPR; \
    VMW; \
    FENCE(); BAR(); FENCE(); \
    { \
        const u16* _a = &ls[(P)*12288 + aOff]; \
        const u16* _b = &ls[(P)*12288 + bOff]; \
        a[0] = *(const bf16x8*)(_a);        a[1] = *(const bf16x8*)(_a + 512); \
        a[2] = *(const bf16x8*)(_a + 1024); a[3] = *(const bf16x8*)(_a + 1536); \
        a[4] = *(const bf16x8*)(_a + 2048); a[5] = *(const bf16x8*)(_a + 2560); \
        a[6] = *(const bf16x8*)(_a + 3072); a[7] = *(const bf16x8*)(_a + 3584); \
        b[0] = *(const bf16x8*)(_b);        b[1] = *(const bf16x8*)(_b + 512); \
        b[2] = *(const bf16x8*)(_b + 1024); b[3] = *(const bf16x8*)(_b + 1536); \
    } \
    WAIT_LGKM0(); SCHEDB(); \
    __builtin_amdgcn_s_setprio(1); \
    MFMA32(); \
    __builtin_amdgcn_s_setprio(0); \
    FENCE(); BAR(); \
} while (0)

__global__ __launch_bounds__(256, 2)
void gemm4_kernel(const u16* __restrict__ Ab, const u16* __restrict__ Wb,
                  const float* __restrict__ bias, float* __restrict__ Out) {
    __shared__ u16 ls[3 * 12288];

    const int tid = threadIdx.x;
    const int w = tid >> 6, lane = tid & 63;
    const int wc = w;                       // 4 N-waves
    const int l15 = lane & 15, lq = lane >> 4;

    // XCD swizzle (1024 blocks % 8 == 0): each XCD gets bn-pair chunks so one
    // 2MB B-panel is L2-resident per XCD round; A panels stream from L3.
    int raw = blockIdx.x;
    int swz = (raw & 7) * 128 + (raw >> 3);
    const int bn = swz >> 6, bm = swz & 63;
    const int m0 = bm * BM, n0 = bn * BN;

    // LDS read bases (elems): logical k-octet lq at physical block lq ^ f(row)
    const int xb = (lq ^ ((l15 >> 1) & 3)) * 8;
    const int aOff = l15 * 32 + xb;                    // + mf*512
    const int bOff = 4096 + (wc * 64 + l15) * 32 + xb; // + nf*512

    // staging: thread t covers LDS row j*64 + (t>>2), physical block t&3
    const int srow = tid >> 2;
    const int gcb = ((tid & 3) ^ ((tid >> 3) & 3)) * 8;
    const u16* pA0 = Ab + (size_t)(m0 + srow) * K_DIM + gcb;
    const u16* pA1 = pA0 + (size_t)64 * K_DIM;
    const u16* pB0 = Wb + (size_t)(n0 + srow) * K_DIM + gcb;
    const u16* pB1 = pB0 + (size_t)64 * K_DIM;
    const u16* pB2 = pB0 + (size_t)128 * K_DIM;
    const u16* pB3 = pB0 + (size_t)192 * K_DIM;
    const int wOff = w * 512;   // wave-uniform LDS dest (elems)

    f32x4 acc[8][4];
#pragma unroll
    for (int mf = 0; mf < 8; ++mf)
#pragma unroll
        for (int nf = 0; nf < 4; ++nf) acc[mf][nf] = (f32x4){0.f, 0.f, 0.f, 0.f};
    bf16x8 a[8], b[4];

    // ---- prologue: stage kt0 -> buf0, kt1 -> buf1 (12 loads in flight) ----
    STG6(0, 0);
    STG6(1, 32);
    pA0 += 64; pA1 += 64; pB0 += 64; pB1 += 64; pB2 += 64; pB3 += 64;

    // ---- main: 42 triples cover kt = 0..125 (each stages kt+2 = 2..127) ----
#pragma unroll 1
    for (int t = 0; t < 42; ++t) {
        PHASE(0, STG6(2, 0),  WAIT_VM12());
        PHASE(1, STG6(0, 32), WAIT_VM12());
        PHASE(2, STG6(1, 64), WAIT_VM12());
        pA0 += 96; pA1 += 96; pB0 += 96; pB1 += 96; pB2 += 96; pB3 += 96;
    }
    // ---- tail: kt=126 (buf0), kt=127 (buf1), no staging ----
    PHASE(0, STG_NONE(), WAIT_VM6());
    PHASE(1, STG_NONE(), WAIT_VM0());

    // ---- epilogue (bias loaded here so it never perturbs the vmcnt ledger) ----
    float bv[4];
#pragma unroll
    for (int nf = 0; nf < 4; ++nf) bv[nf] = bias[n0 + wc * 64 + nf * 16 + l15];
#pragma unroll
    for (int mf = 0; mf < 8; ++mf) {
        const int gm = m0 + mf * 16 + lq * 4;
#pragma unroll
        for (int nf = 0; nf < 4; ++nf) {
            const int gn = n0 + wc * 64 + nf * 16 + l15;
            float* op = Out + (size_t)gm * N_DIM + gn;
#pragma unroll
            for (int j = 0; j < 4; ++j)
                op[(size_t)j * N_DIM] = acc[mf][nf][j] + bv[nf];
        }
    }
}

// ---------------- Fallback: naive fused fp32 ----------------
__global__ void naive_kernel(const float* __restrict__ In, const int* __restrict__ codes,
                             const float* __restrict__ cbs, const float* __restrict__ scales,
                             const float* __restrict__ bias, float* __restrict__ Out) {
    int m = blockIdx.x >> 4;
    int n = ((blockIdx.x & 15) << 8) + threadIdx.x;
    const float* x = In + (size_t)m * K_DIM;
    const int* cr = codes + (size_t)n * 512 * 2;
    float acc = 0.f;
    for (int ig = 0; ig < 512; ++ig) {
        int c0 = cr[ig * 2], c1 = cr[ig * 2 + 1];
        const float* e0 = cbs + (size_t)c0 * 8;
        const float* e1 = cbs + 2048 + (size_t)c1 * 8;
        const float* xx = x + ig * 8;
#pragma unroll
        for (int j = 0; j < 8; ++j) acc += xx[j] * (e0[j] + e1[j]);
    }
    Out[(size_t)m * N_DIM + n] = acc * scales[n] + bias[n];
}

extern "C" void kernel_launch(void* const* d_in, const int* in_sizes, int n_in,
                              void* d_out, int out_size, void* d_ws, size_t ws_size,
                              hipStream_t stream) {
    const float* In     = (const float*)d_in[0];
    const int*   codes  = (const int*)d_in[1];
    const float* cbs    = (const float*)d_in[2];
    const float* scales = (const float*)d_in[3];
    const float* bias   = (const float*)d_in[4];
    float* Out = (float*)d_out;

    const size_t aBytes = (size_t)M_DIM * K_DIM * 2;
    const size_t wBytes = (size_t)N_DIM * K_DIM * 2;
    if (ws_size >= aBytes + wBytes) {
        u16* Ab = (u16*)d_ws;
        u16* Wb = (u16*)((char*)d_ws + aBytes);
        cvt_a_kernel<<<dim3((M_DIM * K_DIM) / (256 * 8)), dim3(256), 0, stream>>>(In, Ab);
        dequant_w_kernel<<<dim3((N_DIM * 512) / 256), dim3(256), 0, stream>>>(codes, cbs, scales, Wb);
        gemm4_kernel<<<dim3((M_DIM / BM) * (N_DIM / BN)), dim3(256), 0, stream>>>(Ab, Wb, bias, Out);
    } else {
        naive_kernel<<<dim3(M_DIM * (N_DIM / 256)), dim3(256), 0, stream>>>(In, codes, cbs, scales, bias, Out);
    }
}